// Round 14
// baseline (212.685 us; speedup 1.0000x reference)
//
#include <hip/hip_runtime.h>

#define LL 8192
#define HH 128

typedef __attribute__((ext_vector_type(8))) short short8v;
typedef __attribute__((ext_vector_type(4))) short short4v;
typedef __attribute__((ext_vector_type(4))) float f32x4;
typedef __attribute__((ext_vector_type(16))) float f32x16;

__device__ inline short f2bf(float f) {
    union { float f; unsigned u; } x; x.f = f;
    unsigned r = (x.u + 0x7fffu + ((x.u >> 16) & 1u)) >> 16;
    return (short)r;
}
__device__ inline float bf2f(short s) {
    union { unsigned u; float f; } x; x.u = ((unsigned)(unsigned short)s) << 16;
    return x.f;
}

// raw 2^x (v_exp_f32). log2e is pre-folded into the Q scale at repack.
__device__ inline float fexp2(float x) {
#if defined(__has_builtin)
#if __has_builtin(__builtin_amdgcn_exp2f)
    return __builtin_amdgcn_exp2f(x);
#else
    return __expf(x * 0.6931471805599453f);
#endif
#else
    return __expf(x * 0.6931471805599453f);
#endif
}

// one v_perm_b32: dest = (hi & 0xffff0000) | (lo >> 16)  (truncating bf16 pair pack)
__device__ inline unsigned pack_hi16(unsigned hi, unsigned lo) {
#if defined(__has_builtin)
#if __has_builtin(__builtin_amdgcn_perm)
    return __builtin_amdgcn_perm(hi, lo, 0x07060302u);
#endif
#endif
    return (lo >> 16) | (hi & 0xffff0000u);
}

// lane[0:31] <-> lane[32:63] half-exchange between two VGPRs (T12).
__device__ inline void plane32swap(unsigned& a, unsigned& b) {
#if defined(__has_builtin)
#if __has_builtin(__builtin_amdgcn_permlane32_swap)
    typedef unsigned u2v __attribute__((ext_vector_type(2)));
    u2v r = __builtin_amdgcn_permlane32_swap(a, b, false, false);
    a = r[0]; b = r[1];
    return;
#endif
#endif
    asm volatile("v_permlane32_swap_b32 %0, %1" : "+v"(a), "+v"(b));
}

// Swizzled LDS pointer (XOR bits 4-6 with row&7); rows of 128 shorts (256B).
// 8B/16B-aligned accesses stay contiguous (bit 3 untouched).
__device__ inline short* sAp(short* base, int row, int col) {
    int byte = (row << 8) + (col << 1);
    byte ^= (row & 7) << 4;
    return (short*)((char*)base + byte);
}

// LN of one 128-float row (global or LDS) per 16-lane group, 8 floats/lane.
__device__ inline short8v ln_pack8(const float* rowF, int l15) {
    const float4 a = *(const float4*)&rowF[l15 * 8];
    const float4 b = *(const float4*)&rowF[l15 * 8 + 4];
    float s  = (a.x + a.y) + (a.z + a.w) + (b.x + b.y) + (b.z + b.w);
    float s2 = a.x * a.x + a.y * a.y + a.z * a.z + a.w * a.w
             + b.x * b.x + b.y * b.y + b.z * b.z + b.w * b.w;
#pragma unroll
    for (int off = 1; off <= 8; off <<= 1) {
        s  += __shfl_xor(s,  off, 64);
        s2 += __shfl_xor(s2, off, 64);
    }
    float mu = s * (1.f / 128.f);
    float var = s2 * (1.f / 128.f) - mu * mu;
    float rstd = rsqrtf(var + 1e-5f);
    short8v r;
    r[0] = f2bf((a.x - mu) * rstd);
    r[1] = f2bf((a.y - mu) * rstd);
    r[2] = f2bf((a.z - mu) * rstd);
    r[3] = f2bf((a.w - mu) * rstd);
    r[4] = f2bf((b.x - mu) * rstd);
    r[5] = f2bf((b.y - mu) * rstd);
    r[6] = f2bf((b.z - mu) * rstd);
    r[7] = f2bf((b.w - mu) * rstd);
    return r;
}

// ---------------------------------------------------------------------------
// repack (r13 output-linear form): conv w -> bf16 [lay][k][o][i]; Wq/Wk/Wv
// stacked bf16 (q-scale AND log2e folded); b3; Wff bf16; h0 = x + PE.
// ---------------------------------------------------------------------------
__global__ __launch_bounds__(256) void repack_all(const float* __restrict__ x,
                                                  const float* __restrict__ w,
                                                  const float* __restrict__ Wq,
                                                  const float* __restrict__ Wk,
                                                  const float* __restrict__ Wv,
                                                  const float* __restrict__ bq,
                                                  const float* __restrict__ bk,
                                                  const float* __restrict__ bv,
                                                  const float* __restrict__ Wff,
                                                  short* __restrict__ wkb,
                                                  short* __restrict__ wqkvb,
                                                  float* __restrict__ b3,
                                                  short* __restrict__ wffb,
                                                  float* __restrict__ h0) {
    const float qs = 0.08838834764831845f * 1.4426950408889634f;  // scale * log2e
    int idx = blockIdx.x * 256 + threadIdx.x;
    if (idx < 458752) {                       // 4*7*128*128, [lay][k][o][i], i fastest
        int i = idx & (HH - 1);
        int t = idx >> 7;
        int o = t & (HH - 1);
        int t2 = t >> 7;
        int k = t2 % 7;
        int lay = t2 / 7;
        wkb[idx] = f2bf(w[((lay * HH + o) * HH + i) * 7 + k]);
    } else {
        int j = idx - 458752;
        if (j < 49152) {                      // stacked QKV weights
            int t = j >> 14, r = j & 16383;
            float v = (t == 0) ? Wq[r] * qs : (t == 1) ? Wk[r] : Wv[r];
            wqkvb[j] = f2bf(v);
        } else if (j < 49536) {               // stacked biases
            int jj = j - 49152;
            b3[jj] = (jj < 128) ? bq[jj] * qs : (jj < 256) ? bk[jj - 128] : bv[jj - 256];
        } else if (j < 65920) {               // FF weights
            int jj = j - 49536;
            wffb[jj] = f2bf(Wff[jj]);
        } else {                              // h0 = x + positional encoding
            int p = j - 65920;                // one float4 per thread, 262144 total
            if (p < 262144) {
                int g = p >> 5, c4 = (p & 31) << 2;
                float4 val = *(const float4*)&x[g * HH + c4];
                float fg = (float)g;
#pragma unroll
                for (int h = 0; h < 2; h++) {
                    int i0 = c4 + h * 2;      // even -> i0 == (i0 & ~1)
                    float e = (float)i0 / 128.f;
                    float rev = fg * fexp2(e * -13.287712379549449f - 2.651496129472319f);
                    rev -= floorf(rev);
                    float ang = rev * 6.283185307179586f;
                    ((float*)&val)[h * 2]     += __sinf(ang);
                    ((float*)&val)[h * 2 + 1] += __cosf(ang);
                }
                *(float4*)&h0[g * HH + c4] = val;
            }
        }
    }
}

// ---------------------------------------------------------------------------
// Barrier-free streaming LN: n = LN(h) as bf16 into a PADDED buffer
// (8 zero rows each side = conv SAME-padding for free). One row per 16-lane
// group, global read -> shuffle reduce -> global write. No LDS, no barriers:
// the LN shuffle chain leaves the conv kernels' critical path entirely
// (r14 theory: the ~70us conv-stack invariant across all fused structures
// was the lockstep LN->conv barrier chain).
// Block 512 zeroes the pad rows. Chunked row map matches the conv/qkv
// consumers so n stays XCD-local in L2.
// ---------------------------------------------------------------------------
__global__ __launch_bounds__(256) void ln_kernel(const float* __restrict__ h,
                                                 short* __restrict__ npad) {
    int tid = threadIdx.x;
    int b = blockIdx.x;
    if (b < 512) {
        int w = tid >> 6, lane = tid & 63;
        int l15 = lane & 15, quad = lane >> 4;
        int row = ((b & 7) * 64 + (b >> 3)) * 16 + w * 4 + quad;
        short8v pk = ln_pack8(&h[row * HH], l15);
        *(short8v*)&npad[(8 + row) * HH + l15 * 8] = pk;
    } else {
        int pr = tid >> 4, c = tid & 15;
        int prow = (pr < 8) ? pr : (8 + LL + (pr - 8));
        *(short8v*)&npad[prow * HH + c * 8] = (short8v)(short)0;
    }
}

// ---------------------------------------------------------------------------
// ONE conv layer from pre-LN'd bf16 input: hout = hin + conv1d(n, w[lay]).
// 2 phases only: stage 22 bf16 rows (5.6 KB LDS, swizzled) -> barrier ->
// 28 MFMA + residual-from-global epilogue. Col-split 2 (legal: no LN inside)
// -> grid 1024 = 4 independent blocks/CU that leapfrog each other's barriers.
// wg = mt + 512*colhalf keeps both halves of an m-tile on the same XCD.
// ---------------------------------------------------------------------------
__global__ __launch_bounds__(256, 4) void conv_lay_kernel(const short* __restrict__ npad,
                                                          const float* __restrict__ hin,
                                                          const short* __restrict__ wkb,
                                                          const float* __restrict__ conv_b,
                                                          float* __restrict__ hout,
                                                          int lay) {
    __shared__ short sN[24 * 128];
    int tid = threadIdx.x;
    int w = tid >> 6, lane = tid & 63;
    int l15 = lane & 15, quad = lane >> 4;
    int wg = blockIdx.x;
    int mt = wg & 511, ch = wg >> 9;
    int m0 = ((mt & 7) * 64 + (mt >> 3)) * 16;       // XCD-chunked m-tile
    int c0w = ch * 64 + w * 16;                      // this wave's 16 channels

    // stage rows m0-3 .. m0+18 (bf16; pad rows are zero)
    const short* nrows = npad + (size_t)(8 + m0 - 3) * HH;
    for (int idx = tid; idx < 22 * 16; idx += 256) {
        int r = idx >> 4, c = idx & 15;
        *(short8v*)sAp(sN, r, c * 8) = *(const short8v*)&nrows[r * HH + c * 8];
    }
    __syncthreads();

    const short* wl = wkb + lay * 7 * HH * HH;
    f32x4 aA = (f32x4)(0.f), aB = (f32x4)(0.f);
#pragma unroll
    for (int k = 0; k < 7; k++) {
        const short* bw = wl + (k * HH + c0w + l15) * HH;
#pragma unroll
        for (int ks = 0; ks < 4; ks++) {
            short8v bf = *(const short8v*)&bw[ks * 32 + quad * 8];
            short8v af = *(const short8v*)sAp(sN, l15 + k, ks * 32 + quad * 8);
            if (ks & 1) aB = __builtin_amdgcn_mfma_f32_16x16x32_bf16(af, bf, aB, 0, 0, 0);
            else        aA = __builtin_amdgcn_mfma_f32_16x16x32_bf16(af, bf, aA, 0, 0, 0);
        }
    }
    float bb = conv_b[lay * HH + c0w + l15];
#pragma unroll
    for (int r = 0; r < 4; r++) {
        int g = m0 + quad * 4 + r;
        hout[g * HH + c0w + l15] = hin[g * HH + c0w + l15] + aA[r] + aB[r] + bb;
    }
}

// ---------------------------------------------------------------------------
// QKV from pre-LN'd n4: grid (512, 3), one of Q/K/V per blockIdx.y.
// A-fragments read directly from global (L2-hot, XCD-local). V transposed
// via per-wave LDS tile.
// ---------------------------------------------------------------------------
__global__ __launch_bounds__(256, 4) void qkv_kernel(const short* __restrict__ n4,
                                                     const short* __restrict__ wqkvb,
                                                     const float* __restrict__ b3,
                                                     short* __restrict__ qb,
                                                     short* __restrict__ kb,
                                                     short* __restrict__ vt) {
    __shared__ short sT[4][32][17];
    int tid = threadIdx.x;
    int w = tid >> 6, lane = tid & 63;
    int l15 = lane & 15, quad = lane >> 4;
    int wg = blockIdx.x;
    int m0 = ((wg & 7) * 64 + (wg >> 3)) * 16;
    int t = blockIdx.y;
    int c0 = w * 32;

    short8v af4[4];
#pragma unroll
    for (int ks = 0; ks < 4; ks++)
        af4[ks] = *(const short8v*)&n4[(size_t)(m0 + l15) * HH + ks * 32 + quad * 8];

    f32x4 acc0 = (f32x4)(0.f), acc1 = (f32x4)(0.f);
    const short* b0 = wqkvb + (t * 128 + c0 + l15) * HH;
    const short* b1 = b0 + 16 * HH;
#pragma unroll
    for (int ks = 0; ks < 4; ks++) {
        short8v bf0 = *(const short8v*)&b0[ks * 32 + quad * 8];
        short8v bf1 = *(const short8v*)&b1[ks * 32 + quad * 8];
        acc0 = __builtin_amdgcn_mfma_f32_16x16x32_bf16(af4[ks], bf0, acc0, 0, 0, 0);
        acc1 = __builtin_amdgcn_mfma_f32_16x16x32_bf16(af4[ks], bf1, acc1, 0, 0, 0);
    }
    float qb0 = b3[t * 128 + c0 + l15], qb1 = b3[t * 128 + c0 + 16 + l15];
    if (t < 2) {
        short* o = (t == 0) ? qb : kb;
#pragma unroll
        for (int r = 0; r < 4; r++) {
            int lr = m0 + quad * 4 + r;
            o[lr * HH + c0 + l15]      = f2bf(acc0[r] + qb0);
            o[lr * HH + c0 + 16 + l15] = f2bf(acc1[r] + qb1);
        }
    } else {
#pragma unroll
        for (int r = 0; r < 4; r++) {
            sT[w][l15][quad * 4 + r]      = f2bf(acc0[r] + qb0);
            sT[w][16 + l15][quad * 4 + r] = f2bf(acc1[r] + qb1);
        }
        asm volatile("s_waitcnt lgkmcnt(0)" ::: "memory");
        __syncthreads();
#pragma unroll
        for (int cc = 0; cc < 8; cc++) {
            int col = cc * 4 + quad;
            vt[(c0 + col) * LL + m0 + l15] = sT[w][col][l15];
        }
    }
}

// ---------------------------------------------------------------------------
// bf16 flash attention (proven 49.0us config): single-buffer, swapped QK^T
// 32x32, in-register softmax (T12), setprio, exp2; nsplit=8 -> grid 512.
// XCD affinity: seg = bid&7 runs on the XCD that produced K/V seg.
// ---------------------------------------------------------------------------
#define FBN 64
#define NSPLIT 8
#define SEGROWS (LL / NSPLIT)

__global__ __launch_bounds__(256, 2) void flash_mfma_kernel(const short* __restrict__ qs,
                                                            const short* __restrict__ ksrc,
                                                            const short* __restrict__ vsrc,
                                                            short* __restrict__ PO,
                                                            float* __restrict__ Pl) {
    __shared__ short sK[16 * 64 * 8];   // 16 KB
    __shared__ short sV[16 * 64 * 8];   // 16 KB

    const int tid = threadIdx.x;
    const int w = tid >> 6, lane = tid & 63;
    const int l31 = lane & 31, hi = lane >> 5;
    const int seg = blockIdx.x & 7;              // XCD-affine segment
    const int m0 = (blockIdx.x >> 3) * 128;
    const int jbeg = seg * SEGROWS;
    const int nchunk = SEGROWS >> 6;             // 16
    const int qrow = m0 + w * 32 + l31;

    short8v qf[8];
#pragma unroll
    for (int ks = 0; ks < 8; ks++)
        qf[ks] = *(const short8v*)&qs[qrow * HH + ks * 16 + hi * 8];

    float l_r = 0.f;
    f32x16 o_acc[4];
#pragma unroll
    for (int dt = 0; dt < 4; dt++) o_acc[dt] = (f32x16)(0.f);

    short8v kr[4], vr[4];
#pragma unroll
    for (int r = 0; r < 4; r++) {
        int s = w + 4 * r;
        kr[r] = *(const short8v*)&ksrc[(jbeg + (s >> 3) * 32 + l31) * HH + (s & 7) * 16 + hi * 8];
        vr[r] = *(const short8v*)&vsrc[((s >> 2) * 32 + l31) * LL + jbeg + (s & 3) * 16 + hi * 8];
    }

    for (int c = 0; c < nchunk; c++) {
        __syncthreads();
#pragma unroll
        for (int r = 0; r < 4; r++) {
            int s = w + 4 * r;
            *(short8v*)&sK[(s * 64 + lane) * 8] = kr[r];
            *(short8v*)&sV[(s * 64 + lane) * 8] = vr[r];
        }
        __syncthreads();
        if (c + 1 < nchunk) {
            const int j1 = jbeg + (c + 1) * FBN;
#pragma unroll
            for (int r = 0; r < 4; r++) {
                int s = w + 4 * r;
                kr[r] = *(const short8v*)&ksrc[(j1 + (s >> 3) * 32 + l31) * HH + (s & 7) * 16 + hi * 8];
                vr[r] = *(const short8v*)&vsrc[((s >> 2) * 32 + l31) * LL + j1 + (s & 3) * 16 + hi * 8];
            }
        }
        // ---- S^T = K Q^T ----
        f32x16 s0 = (f32x16)(0.f), s1 = (f32x16)(0.f);
        __builtin_amdgcn_s_setprio(1);
#pragma unroll
        for (int ks = 0; ks < 8; ks++) {
            short8v kf0 = *(const short8v*)&sK[((ks) * 64 + lane) * 8];
            short8v kf1 = *(const short8v*)&sK[((8 + ks) * 64 + lane) * 8];
            s0 = __builtin_amdgcn_mfma_f32_32x32x16_bf16(kf0, qf[ks], s0, 0, 0, 0);
            s1 = __builtin_amdgcn_mfma_f32_32x32x16_bf16(kf1, qf[ks], s1, 0, 0, 0);
        }
        __builtin_amdgcn_s_setprio(0);
        // ---- softmax + in-register P->A-frag (per 32-kv tile, T12) ----
        short8v pfrag[4];
#pragma unroll
        for (int nt = 0; nt < 2; nt++) {
            const f32x16& sa = nt ? s1 : s0;
            unsigned pw[8];
#pragma unroll
            for (int m = 0; m < 8; m++) {
                float p0 = fexp2(sa[2 * m]);
                float p1 = fexp2(sa[2 * m + 1]);
                l_r += p0 + p1;
                union { float f; unsigned u; } u0, u1;
                u0.f = p0; u1.f = p1;
                pw[m] = pack_hi16(u1.u, u0.u);
            }
            plane32swap(pw[0], pw[2]);
            plane32swap(pw[1], pw[3]);
            plane32swap(pw[4], pw[6]);
            plane32swap(pw[5], pw[7]);
            union { unsigned u[4]; short8v v; } fa, fb;
            fa.u[0] = pw[0]; fa.u[1] = pw[1]; fa.u[2] = pw[2]; fa.u[3] = pw[3];
            fb.u[0] = pw[4]; fb.u[1] = pw[5]; fb.u[2] = pw[6]; fb.u[3] = pw[7];
            pfrag[nt * 2]     = fa.v;
            pfrag[nt * 2 + 1] = fb.v;
        }
        // ---- O += P V ----
        __builtin_amdgcn_s_setprio(1);
#pragma unroll
        for (int ks = 0; ks < 4; ks++)
#pragma unroll
            for (int dt = 0; dt < 4; dt++) {
                short8v vf = *(const short8v*)&sV[((dt * 4 + ks) * 64 + lane) * 8];
                o_acc[dt] = __builtin_amdgcn_mfma_f32_32x32x16_bf16(pfrag[ks], vf, o_acc[dt], 0, 0, 0);
            }
        __builtin_amdgcn_s_setprio(0);
    }
    // ---- finalize l ----
    float lsum = l_r + __shfl_xor(l_r, 32, 64);
    if (hi == 0)
        Pl[seg * LL + qrow] = lsum;
    // ---- write bf16 partials ----
#pragma unroll
    for (int dt = 0; dt < 4; dt++)
#pragma unroll
        for (int i = 0; i < 16; i++) {
            int qr = (i & 3) + 8 * (i >> 2) + 4 * hi;
            PO[(size_t)seg * LL * HH + (size_t)(m0 + w * 32 + qr) * HH + dt * 32 + l31] =
                f2bf(o_acc[dt][i]);
        }
}

// ---------------------------------------------------------------------------
// fused attention-merge + residual + LN + FF gemm + relu + residual -> out.
// ---------------------------------------------------------------------------
__global__ __launch_bounds__(256) void ff_kernel(const float* __restrict__ hin,
                                                 const short* __restrict__ PO,
                                                 const float* __restrict__ Pl,
                                                 const short* __restrict__ wffb,
                                                 const float* __restrict__ bff,
                                                 float* __restrict__ out) {
    __shared__ float sF[16][132];
    __shared__ short sA[16 * 128];
    __shared__ float sLi[16];
    int tid = threadIdx.x;
    int w = tid >> 6, lane = tid & 63;
    int l15 = lane & 15, quad = lane >> 4;
    int wg = blockIdx.x;
    int m0 = ((wg & 7) * 64 + (wg >> 3)) * 16;

    if (tid < 16) {
        float s = 0.f;
#pragma unroll
        for (int seg = 0; seg < NSPLIT; seg++) s += Pl[seg * LL + m0 + tid];
        sLi[tid] = 1.f / s;
    }
    __syncthreads();
    for (int idx = tid; idx < 16 * 32; idx += 256) {
        int r = idx >> 5, c4 = (idx & 31) << 2;
        float4 hv = *(const float4*)&hin[(m0 + r) * HH + c4];
        float s0 = 0.f, s1 = 0.f, s2 = 0.f, s3 = 0.f;
#pragma unroll
        for (int seg = 0; seg < NSPLIT; seg++) {
            short4v pv = *(const short4v*)&PO[(size_t)seg * LL * HH + (m0 + r) * HH + c4];
            s0 += bf2f(pv[0]); s1 += bf2f(pv[1]); s2 += bf2f(pv[2]); s3 += bf2f(pv[3]);
        }
        float li = sLi[r];
        *(float4*)&sF[r][c4] = make_float4(hv.x + s0 * li, hv.y + s1 * li,
                                           hv.z + s2 * li, hv.w + s3 * li);
    }
    __syncthreads();
    {
        int row = w * 4 + quad;
        *(short8v*)sAp(sA, row, l15 * 8) = ln_pack8(&sF[row][0], l15);
    }
    __syncthreads();
    int c0 = w * 32;
    f32x4 acc0 = (f32x4)(0.f), acc1 = (f32x4)(0.f);
    const short* b0 = wffb + (c0 + l15) * HH;
    const short* b1 = b0 + 16 * HH;
#pragma unroll
    for (int ks = 0; ks < 4; ks++) {
        short8v af = *(const short8v*)sAp(sA, l15, ks * 32 + quad * 8);
        short8v bf0 = *(const short8v*)&b0[ks * 32 + quad * 8];
        short8v bf1 = *(const short8v*)&b1[ks * 32 + quad * 8];
        acc0 = __builtin_amdgcn_mfma_f32_16x16x32_bf16(af, bf0, acc0, 0, 0, 0);
        acc1 = __builtin_amdgcn_mfma_f32_16x16x32_bf16(af, bf1, acc1, 0, 0, 0);
    }
    float bb0 = bff[c0 + l15], bb1 = bff[c0 + 16 + l15];
#pragma unroll
    for (int r = 0; r < 4; r++) {
        int lr = quad * 4 + r;
        out[(m0 + lr) * HH + c0 + l15]      = fmaxf(acc0[r] + bb0, 0.f) + sF[lr][c0 + l15];
        out[(m0 + lr) * HH + c0 + 16 + l15] = fmaxf(acc1[r] + bb1, 0.f) + sF[lr][c0 + 16 + l15];
    }
}

// ---------------------------------------------------------------------------
extern "C" void kernel_launch(void* const* d_in, const int* in_sizes, int n_in,
                              void* d_out, int out_size, void* d_ws, size_t ws_size,
                              hipStream_t stream) {
    const float* x      = (const float*)d_in[0];
    const float* conv_w = (const float*)d_in[1];
    const float* conv_b = (const float*)d_in[2];
    const float* Wq = (const float*)d_in[3];
    const float* bq = (const float*)d_in[4];
    const float* Wk = (const float*)d_in[5];
    const float* bk = (const float*)d_in[6];
    const float* Wv = (const float*)d_in[7];
    const float* bv = (const float*)d_in[8];
    const float* Wff = (const float*)d_in[9];
    const float* bff = (const float*)d_in[10];
    float* out = (float*)d_out;

    char* ws = (char*)d_ws;
    const size_t MB = 1u << 20;
    float* hB   = (float*)(ws);                              // 4 MB (h4, lives to end)
    short* qb   = (short*)(ws + 4 * MB);                     // 2 MB
    short* kb   = (short*)(ws + 6 * MB);                     // 2 MB
    short* vt   = (short*)(ws + 8 * MB);                     // 2 MB
    float* Pl   = (float*)(ws + 10 * MB);                    // 256 KB (8 segs)
    short* wffb = (short*)(ws + 10 * MB + 524288);           // 32 KB
    short* PO   = (short*)(ws + 10 * MB + 524288 + 32768);   // 16 MB bf16 (nsplit=8)
    // pre-flash-only buffers, aliased inside the PO span (dead before flash):
    short* npad  = (short*)(ws + 12 * MB);                   // 2.1 MB padded LN buf
    short* wkb   = (short*)(ws + 16 * MB);                   // 896 KB
    short* wqkvb = (short*)(ws + 17 * MB);                   // 96 KB
    float* b3    = (float*)(ws + 17 * MB + 131072);          // 1.5 KB
    float* h0    = (float*)(ws + 18 * MB);                   // 4 MB (x+PE; dead after conv0)
    float* h13   = (float*)(ws + 22 * MB);                   // 4 MB (h1/h3 ping)
    float* h2    = h0;                                       // h2 reuses h0 slab
    short* n4    = npad + 8 * HH;                            // unpadded view

    repack_all<<<3074, 256, 0, stream>>>(x, conv_w, Wq, Wk, Wv, bq, bk, bv, Wff,
                                         wkb, wqkvb, b3, wffb, h0);
    ln_kernel<<<513, 256, 0, stream>>>(h0, npad);
    conv_lay_kernel<<<1024, 256, 0, stream>>>(npad, h0,  wkb, conv_b, h13, 0);
    ln_kernel<<<513, 256, 0, stream>>>(h13, npad);
    conv_lay_kernel<<<1024, 256, 0, stream>>>(npad, h13, wkb, conv_b, h2,  1);
    ln_kernel<<<513, 256, 0, stream>>>(h2, npad);
    conv_lay_kernel<<<1024, 256, 0, stream>>>(npad, h2,  wkb, conv_b, h13, 2);
    ln_kernel<<<513, 256, 0, stream>>>(h13, npad);
    conv_lay_kernel<<<1024, 256, 0, stream>>>(npad, h13, wkb, conv_b, hB,  3);
    ln_kernel<<<513, 256, 0, stream>>>(hB, npad);
    qkv_kernel<<<dim3(512, 3), 256, 0, stream>>>(n4, wqkvb, b3, qb, kb, vt);
    flash_mfma_kernel<<<LL / 128 * NSPLIT, 256, 0, stream>>>(qb, kb, vt, PO, Pl);
    ff_kernel<<<LL / 16, 256, 0, stream>>>(hB, PO, Pl, wffb, bff, out);
}

// Round 15
// 191.087 us; speedup vs baseline: 1.1130x; 1.1130x over previous
//
#include <hip/hip_runtime.h>

#define LL 8192
#define HH 128

typedef __attribute__((ext_vector_type(8))) short short8v;
typedef __attribute__((ext_vector_type(4))) short short4v;
typedef __attribute__((ext_vector_type(4))) float f32x4;
typedef __attribute__((ext_vector_type(16))) float f32x16;

__device__ inline short f2bf(float f) {
    union { float f; unsigned u; } x; x.f = f;
    unsigned r = (x.u + 0x7fffu + ((x.u >> 16) & 1u)) >> 16;
    return (short)r;
}
__device__ inline float bf2f(short s) {
    union { unsigned u; float f; } x; x.u = ((unsigned)(unsigned short)s) << 16;
    return x.f;
}

// raw 2^x (v_exp_f32). log2e is pre-folded into the Q scale at repack.
__device__ inline float fexp2(float x) {
#if defined(__has_builtin)
#if __has_builtin(__builtin_amdgcn_exp2f)
    return __builtin_amdgcn_exp2f(x);
#else
    return __expf(x * 0.6931471805599453f);
#endif
#else
    return __expf(x * 0.6931471805599453f);
#endif
}

// one v_perm_b32: dest = (hi & 0xffff0000) | (lo >> 16)  (truncating bf16 pair pack)
__device__ inline unsigned pack_hi16(unsigned hi, unsigned lo) {
#if defined(__has_builtin)
#if __has_builtin(__builtin_amdgcn_perm)
    return __builtin_amdgcn_perm(hi, lo, 0x07060302u);
#endif
#endif
    return (lo >> 16) | (hi & 0xffff0000u);
}

// lane[0:31] <-> lane[32:63] half-exchange between two VGPRs (T12).
__device__ inline void plane32swap(unsigned& a, unsigned& b) {
#if defined(__has_builtin)
#if __has_builtin(__builtin_amdgcn_permlane32_swap)
    typedef unsigned u2v __attribute__((ext_vector_type(2)));
    u2v r = __builtin_amdgcn_permlane32_swap(a, b, false, false);
    a = r[0]; b = r[1];
    return;
#endif
#endif
    asm volatile("v_permlane32_swap_b32 %0, %1" : "+v"(a), "+v"(b));
}

// Swizzled LDS pointer (XOR bits 4-6 with row&7); rows of 128 shorts (256B).
__device__ inline short* sAp(short* base, int row, int col) {
    int byte = (row << 8) + (col << 1);
    byte ^= (row & 7) << 4;
    return (short*)((char*)base + byte);
}

// LN of one 128-float LDS row per 16-lane group, 8 floats/lane.
__device__ inline short8v ln_pack8(const float* rowF, int l15) {
    const float4 a = *(const float4*)&rowF[l15 * 8];
    const float4 b = *(const float4*)&rowF[l15 * 8 + 4];
    float s  = (a.x + a.y) + (a.z + a.w) + (b.x + b.y) + (b.z + b.w);
    float s2 = a.x * a.x + a.y * a.y + a.z * a.z + a.w * a.w
             + b.x * b.x + b.y * b.y + b.z * b.z + b.w * b.w;
#pragma unroll
    for (int off = 1; off <= 8; off <<= 1) {
        s  += __shfl_xor(s,  off, 64);
        s2 += __shfl_xor(s2, off, 64);
    }
    float mu = s * (1.f / 128.f);
    float var = s2 * (1.f / 128.f) - mu * mu;
    float rstd = rsqrtf(var + 1e-5f);
    short8v r;
    r[0] = f2bf((a.x - mu) * rstd);
    r[1] = f2bf((a.y - mu) * rstd);
    r[2] = f2bf((a.z - mu) * rstd);
    r[3] = f2bf((a.w - mu) * rstd);
    r[4] = f2bf((b.x - mu) * rstd);
    r[5] = f2bf((b.y - mu) * rstd);
    r[6] = f2bf((b.z - mu) * rstd);
    r[7] = f2bf((b.w - mu) * rstd);
    return r;
}

// ---------------------------------------------------------------------------
// repack: conv w -> bf16 [lay][k][o][i] (output-linear, coalesced stores);
// Wq/Wk/Wv stacked bf16 (q-scale AND log2e folded); b3; Wff bf16.
// (h0/PE branch removed -- PE is now inlined in conv4 staging.)
// ---------------------------------------------------------------------------
__global__ __launch_bounds__(256) void repack_all(const float* __restrict__ w,
                                                  const float* __restrict__ Wq,
                                                  const float* __restrict__ Wk,
                                                  const float* __restrict__ Wv,
                                                  const float* __restrict__ bq,
                                                  const float* __restrict__ bk,
                                                  const float* __restrict__ bv,
                                                  const float* __restrict__ Wff,
                                                  short* __restrict__ wkb,
                                                  short* __restrict__ wqkvb,
                                                  float* __restrict__ b3,
                                                  short* __restrict__ wffb) {
    const float qs = 0.08838834764831845f * 1.4426950408889634f;  // scale * log2e
    int idx = blockIdx.x * 256 + threadIdx.x;
    if (idx < 458752) {                       // 4*7*128*128, [lay][k][o][i], i fastest
        int i = idx & (HH - 1);
        int t = idx >> 7;
        int o = t & (HH - 1);
        int t2 = t >> 7;
        int k = t2 % 7;
        int lay = t2 / 7;
        wkb[idx] = f2bf(w[((lay * HH + o) * HH + i) * 7 + k]);
    } else {
        int j = idx - 458752;
        if (j < 49152) {                      // stacked QKV weights
            int t = j >> 14, r = j & 16383;
            float v = (t == 0) ? Wq[r] * qs : (t == 1) ? Wk[r] : Wv[r];
            wqkvb[j] = f2bf(v);
        } else if (j < 49536) {               // stacked biases
            int jj = j - 49152;
            b3[jj] = (jj < 128) ? bq[jj] * qs : (jj < 256) ? bk[jj - 128] : bv[jj - 256];
        } else if (j < 65920) {               // FF weights
            int jj = j - 49536;
            wffb[jj] = f2bf(Wff[jj]);
        }
    }
}

// ---------------------------------------------------------------------------
// FULLY FUSED conv stack + QKV (r13 body + INLINE PE in staging):
// reads x directly, adds fast-PE per staged element (cheap: ~20 VALU per
// float4, ~100/thread) -- deletes the h0 buffer and an 8MB HBM round trip.
// Structure unchanged: stage 40 rows (halo +-12); exact per-layer halos via
// masked partial m-tiles (L0: 3/19/35[mask<2], L1: 6/22[mask<12],
// L2: 9/25[mask<6], L3: core 12); per-layer shared weights. Grid 512,
// XCD-chunked m.
// ---------------------------------------------------------------------------
__global__ __launch_bounds__(256, 2) void conv4_qkv_kernel(const float* __restrict__ x,
                                                           const short* __restrict__ wkb,
                                                           const float* __restrict__ conv_b,
                                                           const short* __restrict__ wqkvb,
                                                           const float* __restrict__ b3,
                                                           float* __restrict__ hB,
                                                           short* __restrict__ qb,
                                                           short* __restrict__ kb,
                                                           short* __restrict__ vt) {
    __shared__ float sF[40][132];
    __shared__ short sA[54 * 128];   // 40 live rows; partial tiles over-read to row 53
    __shared__ short sT[4][32][17];
    int tid = threadIdx.x;
    int w = tid >> 6, lane = tid & 63;
    int l15 = lane & 15, quad = lane >> 4;
    int wg = blockIdx.x;
    int m0 = ((wg & 7) * 64 + (wg >> 3)) * 16;       // XCD-chunked m-tile
    int c0 = w * 32;

    // ---- stage rows m0-12 .. m0+27 from x, PE added inline ----
    for (int idx = tid; idx < 40 * 32; idx += 256) {
        int r = idx >> 5, c4 = (idx & 31) << 2;
        int g = m0 - 12 + r;
        float4 val = make_float4(0.f, 0.f, 0.f, 0.f);
        if (g >= 0 && g < LL) {
            val = *(const float4*)&x[g * HH + c4];
            float fg = (float)g;
#pragma unroll
            for (int h = 0; h < 2; h++) {
                int i0 = c4 + h * 2;      // even -> i0 == (i0 & ~1)
                float e = (float)i0 / 128.f;
                // rev = g * 10000^-e / (2*pi); 2^(-e*log2(1e4) - log2(2pi))
                float rev = fg * fexp2(e * -13.287712379549449f - 2.651496129472319f);
                rev -= floorf(rev);
                float ang = rev * 6.283185307179586f;
                ((float*)&val)[h * 2]     += __sinf(ang);
                ((float*)&val)[h * 2 + 1] += __cosf(ang);
            }
        }
        *(float4*)&sF[r][c4] = val;
    }
    __syncthreads();
    // ---- LN rows 0..39 (OOB rows are zero -> LN -> 0 naturally) ----
#pragma unroll
    for (int rr = 0; rr < 3; rr++) {
        int row = rr * 16 + w * 4 + quad;
        if (row < 40)
            *(short8v*)sAp(sA, row, l15 * 8) = ln_pack8(&sF[row][0], l15);
    }
    __syncthreads();

    const float* cb = conv_b;

    // ================= layer 0: 3 tiles (bases 3,19,35), shared weights ====
    {
        const short* wl = wkb + 0 * 7 * HH * HH;
        f32x4 a0a = (f32x4)(0.f), a0b = (f32x4)(0.f);
        f32x4 a1a = (f32x4)(0.f), a1b = (f32x4)(0.f);
        f32x4 a2a = (f32x4)(0.f), a2b = (f32x4)(0.f);
#pragma unroll
        for (int k = 0; k < 7; k++) {
            const short* bw0 = wl + (k * HH + c0 + l15) * HH;
            const short* bw1 = bw0 + 16 * HH;
#pragma unroll
            for (int ks = 0; ks < 4; ks++) {
                short8v bf0 = *(const short8v*)&bw0[ks * 32 + quad * 8];
                short8v bf1 = *(const short8v*)&bw1[ks * 32 + quad * 8];
                short8v af0 = *(const short8v*)sAp(sA,      l15 + k, ks * 32 + quad * 8);
                short8v af1 = *(const short8v*)sAp(sA, 16 + l15 + k, ks * 32 + quad * 8);
                short8v af2 = *(const short8v*)sAp(sA, 32 + l15 + k, ks * 32 + quad * 8);
                a0a = __builtin_amdgcn_mfma_f32_16x16x32_bf16(af0, bf0, a0a, 0, 0, 0);
                a0b = __builtin_amdgcn_mfma_f32_16x16x32_bf16(af0, bf1, a0b, 0, 0, 0);
                a1a = __builtin_amdgcn_mfma_f32_16x16x32_bf16(af1, bf0, a1a, 0, 0, 0);
                a1b = __builtin_amdgcn_mfma_f32_16x16x32_bf16(af1, bf1, a1b, 0, 0, 0);
                a2a = __builtin_amdgcn_mfma_f32_16x16x32_bf16(af2, bf0, a2a, 0, 0, 0);
                a2b = __builtin_amdgcn_mfma_f32_16x16x32_bf16(af2, bf1, a2b, 0, 0, 0);
            }
        }
        float bl = cb[0 * HH + c0 + l15], bh = cb[0 * HH + c0 + 16 + l15];
#pragma unroll
        for (int r = 0; r < 4; r++) {
            int rr0 = quad * 4 + r;
            sF[3 + rr0][c0 + l15]       += a0a[r] + bl;    // rows 3..18
            sF[3 + rr0][c0 + 16 + l15]  += a0b[r] + bh;
            sF[19 + rr0][c0 + l15]      += a1a[r] + bl;    // rows 19..34
            sF[19 + rr0][c0 + 16 + l15] += a1b[r] + bh;
            if (rr0 < 2) {                                 // rows 35..36
                sF[35 + rr0][c0 + l15]      += a2a[r] + bl;
                sF[35 + rr0][c0 + 16 + l15] += a2b[r] + bh;
            }
        }
    }
    __syncthreads();
    // LN rows 3..36 (OOB zero guard)
#pragma unroll
    for (int rr = 0; rr < 3; rr++) {
        int row = 3 + rr * 16 + w * 4 + quad;
        if (row < 37) {
            short8v pk = ln_pack8(&sF[row][0], l15);
            int g = m0 - 12 + row;
            if (g < 0 || g >= LL) pk = (short8v)(short)0;
            *(short8v*)sAp(sA, row, l15 * 8) = pk;
        }
    }
    __syncthreads();

    // ================= layer 1: 2 tiles (bases 6,22), shared weights =======
    {
        const short* wl = wkb + 1 * 7 * HH * HH;
        f32x4 a0a = (f32x4)(0.f), a0b = (f32x4)(0.f);
        f32x4 a1a = (f32x4)(0.f), a1b = (f32x4)(0.f);
#pragma unroll
        for (int k = 0; k < 7; k++) {
            const short* bw0 = wl + (k * HH + c0 + l15) * HH;
            const short* bw1 = bw0 + 16 * HH;
#pragma unroll
            for (int ks = 0; ks < 4; ks++) {
                short8v bf0 = *(const short8v*)&bw0[ks * 32 + quad * 8];
                short8v bf1 = *(const short8v*)&bw1[ks * 32 + quad * 8];
                short8v af0 = *(const short8v*)sAp(sA,  3 + l15 + k, ks * 32 + quad * 8);
                short8v af1 = *(const short8v*)sAp(sA, 19 + l15 + k, ks * 32 + quad * 8);
                a0a = __builtin_amdgcn_mfma_f32_16x16x32_bf16(af0, bf0, a0a, 0, 0, 0);
                a0b = __builtin_amdgcn_mfma_f32_16x16x32_bf16(af0, bf1, a0b, 0, 0, 0);
                a1a = __builtin_amdgcn_mfma_f32_16x16x32_bf16(af1, bf0, a1a, 0, 0, 0);
                a1b = __builtin_amdgcn_mfma_f32_16x16x32_bf16(af1, bf1, a1b, 0, 0, 0);
            }
        }
        float bl = cb[1 * HH + c0 + l15], bh = cb[1 * HH + c0 + 16 + l15];
#pragma unroll
        for (int r = 0; r < 4; r++) {
            int rr0 = quad * 4 + r;
            sF[6 + rr0][c0 + l15]      += a0a[r] + bl;     // rows 6..21
            sF[6 + rr0][c0 + 16 + l15] += a0b[r] + bh;
            if (rr0 < 12) {                                // rows 22..33
                sF[22 + rr0][c0 + l15]      += a1a[r] + bl;
                sF[22 + rr0][c0 + 16 + l15] += a1b[r] + bh;
            }
        }
    }
    __syncthreads();
    // LN rows 6..33 (OOB zero guard)
#pragma unroll
    for (int rr = 0; rr < 2; rr++) {
        int row = 6 + rr * 16 + w * 4 + quad;
        if (row < 34) {
            short8v pk = ln_pack8(&sF[row][0], l15);
            int g = m0 - 12 + row;
            if (g < 0 || g >= LL) pk = (short8v)(short)0;
            *(short8v*)sAp(sA, row, l15 * 8) = pk;
        }
    }
    __syncthreads();

    // ================= layer 2: 2 tiles (bases 9,25), shared weights =======
    {
        const short* wl = wkb + 2 * 7 * HH * HH;
        f32x4 a0a = (f32x4)(0.f), a0b = (f32x4)(0.f);
        f32x4 a1a = (f32x4)(0.f), a1b = (f32x4)(0.f);
#pragma unroll
        for (int k = 0; k < 7; k++) {
            const short* bw0 = wl + (k * HH + c0 + l15) * HH;
            const short* bw1 = bw0 + 16 * HH;
#pragma unroll
            for (int ks = 0; ks < 4; ks++) {
                short8v bf0 = *(const short8v*)&bw0[ks * 32 + quad * 8];
                short8v bf1 = *(const short8v*)&bw1[ks * 32 + quad * 8];
                short8v af0 = *(const short8v*)sAp(sA,  6 + l15 + k, ks * 32 + quad * 8);
                short8v af1 = *(const short8v*)sAp(sA, 22 + l15 + k, ks * 32 + quad * 8);
                a0a = __builtin_amdgcn_mfma_f32_16x16x32_bf16(af0, bf0, a0a, 0, 0, 0);
                a0b = __builtin_amdgcn_mfma_f32_16x16x32_bf16(af0, bf1, a0b, 0, 0, 0);
                a1a = __builtin_amdgcn_mfma_f32_16x16x32_bf16(af1, bf0, a1a, 0, 0, 0);
                a1b = __builtin_amdgcn_mfma_f32_16x16x32_bf16(af1, bf1, a1b, 0, 0, 0);
            }
        }
        float bl = cb[2 * HH + c0 + l15], bh = cb[2 * HH + c0 + 16 + l15];
#pragma unroll
        for (int r = 0; r < 4; r++) {
            int rr0 = quad * 4 + r;
            sF[9 + rr0][c0 + l15]      += a0a[r] + bl;     // rows 9..24
            sF[9 + rr0][c0 + 16 + l15] += a0b[r] + bh;
            if (rr0 < 6) {                                 // rows 25..30
                sF[25 + rr0][c0 + l15]      += a1a[r] + bl;
                sF[25 + rr0][c0 + 16 + l15] += a1b[r] + bh;
            }
        }
    }
    __syncthreads();
    // LN rows 9..30 (OOB zero guard)
#pragma unroll
    for (int rr = 0; rr < 2; rr++) {
        int row = 9 + rr * 16 + w * 4 + quad;
        if (row < 31) {
            short8v pk = ln_pack8(&sF[row][0], l15);
            int g = m0 - 12 + row;
            if (g < 0 || g >= LL) pk = (short8v)(short)0;
            *(short8v*)sAp(sA, row, l15 * 8) = pk;
        }
    }
    __syncthreads();

    // ================= layer 3: core tile (base 12) -> sF + hB =============
    {
        const short* wl = wkb + 3 * 7 * HH * HH;
        f32x4 a0a = (f32x4)(0.f), a0b = (f32x4)(0.f);
#pragma unroll
        for (int k = 0; k < 7; k++) {
            const short* bw0 = wl + (k * HH + c0 + l15) * HH;
            const short* bw1 = bw0 + 16 * HH;
#pragma unroll
            for (int ks = 0; ks < 4; ks++) {
                short8v bf0 = *(const short8v*)&bw0[ks * 32 + quad * 8];
                short8v bf1 = *(const short8v*)&bw1[ks * 32 + quad * 8];
                short8v af = *(const short8v*)sAp(sA, 9 + l15 + k, ks * 32 + quad * 8);
                a0a = __builtin_amdgcn_mfma_f32_16x16x32_bf16(af, bf0, a0a, 0, 0, 0);
                a0b = __builtin_amdgcn_mfma_f32_16x16x32_bf16(af, bf1, a0b, 0, 0, 0);
            }
        }
        float bl = cb[3 * HH + c0 + l15], bh = cb[3 * HH + c0 + 16 + l15];
#pragma unroll
        for (int r = 0; r < 4; r++) {
            int rr0 = quad * 4 + r;
            int g = m0 + rr0;
            float v0 = sF[12 + rr0][c0 + l15]      + a0a[r] + bl;
            float v1 = sF[12 + rr0][c0 + 16 + l15] + a0b[r] + bh;
            sF[12 + rr0][c0 + l15]      = v0;
            sF[12 + rr0][c0 + 16 + l15] = v1;
            hB[g * HH + c0 + l15]      = v0;
            hB[g * HH + c0 + 16 + l15] = v1;
        }
    }
    __syncthreads();
    // ---- LN core rows (sF 12..27) -> sA rows 0..15 ----
    {
        int row = w * 4 + quad;
        *(short8v*)sAp(sA, row, l15 * 8) = ln_pack8(&sF[12 + row][0], l15);
    }
    __syncthreads();
    // ---- QKV gemms ----
    short8v af4[4];
#pragma unroll
    for (int ks = 0; ks < 4; ks++)
        af4[ks] = *(const short8v*)sAp(sA, l15, ks * 32 + quad * 8);

#pragma unroll
    for (int t = 0; t < 3; t++) {
        f32x4 acc0 = (f32x4)(0.f), acc1 = (f32x4)(0.f);
        const short* b0 = wqkvb + (t * 128 + c0 + l15) * HH;
        const short* b1 = b0 + 16 * HH;
#pragma unroll
        for (int ks = 0; ks < 4; ks++) {
            short8v bf0 = *(const short8v*)&b0[ks * 32 + quad * 8];
            short8v bf1 = *(const short8v*)&b1[ks * 32 + quad * 8];
            acc0 = __builtin_amdgcn_mfma_f32_16x16x32_bf16(af4[ks], bf0, acc0, 0, 0, 0);
            acc1 = __builtin_amdgcn_mfma_f32_16x16x32_bf16(af4[ks], bf1, acc1, 0, 0, 0);
        }
        float qb0 = b3[t * 128 + c0 + l15], qb1 = b3[t * 128 + c0 + 16 + l15];
        if (t < 2) {
            short* o = (t == 0) ? qb : kb;
#pragma unroll
            for (int r = 0; r < 4; r++) {
                int lr = m0 + quad * 4 + r;
                o[lr * HH + c0 + l15]      = f2bf(acc0[r] + qb0);
                o[lr * HH + c0 + 16 + l15] = f2bf(acc1[r] + qb1);
            }
        } else {
#pragma unroll
            for (int r = 0; r < 4; r++) {
                sT[w][l15][quad * 4 + r]      = f2bf(acc0[r] + qb0);
                sT[w][16 + l15][quad * 4 + r] = f2bf(acc1[r] + qb1);
            }
            asm volatile("s_waitcnt lgkmcnt(0)" ::: "memory");
#pragma unroll
            for (int cc = 0; cc < 8; cc++) {
                int col = cc * 4 + quad;
                vt[(c0 + col) * LL + m0 + l15] = sT[w][col][l15];
            }
        }
    }
}

// ---------------------------------------------------------------------------
// bf16 flash attention (proven 49.0us config): single-buffer, swapped QK^T
// 32x32, in-register softmax (T12), setprio, exp2; nsplit=8 -> grid 512.
// XCD affinity: seg = bid&7 runs on the XCD that produced K/V seg.
// ---------------------------------------------------------------------------
#define FBN 64
#define NSPLIT 8
#define SEGROWS (LL / NSPLIT)

__global__ __launch_bounds__(256, 2) void flash_mfma_kernel(const short* __restrict__ qs,
                                                            const short* __restrict__ ksrc,
                                                            const short* __restrict__ vsrc,
                                                            short* __restrict__ PO,
                                                            float* __restrict__ Pl) {
    __shared__ short sK[16 * 64 * 8];   // 16 KB
    __shared__ short sV[16 * 64 * 8];   // 16 KB

    const int tid = threadIdx.x;
    const int w = tid >> 6, lane = tid & 63;
    const int l31 = lane & 31, hi = lane >> 5;
    const int seg = blockIdx.x & 7;              // XCD-affine segment
    const int m0 = (blockIdx.x >> 3) * 128;
    const int jbeg = seg * SEGROWS;
    const int nchunk = SEGROWS >> 6;             // 16
    const int qrow = m0 + w * 32 + l31;

    short8v qf[8];
#pragma unroll
    for (int ks = 0; ks < 8; ks++)
        qf[ks] = *(const short8v*)&qs[qrow * HH + ks * 16 + hi * 8];

    float l_r = 0.f;
    f32x16 o_acc[4];
#pragma unroll
    for (int dt = 0; dt < 4; dt++) o_acc[dt] = (f32x16)(0.f);

    short8v kr[4], vr[4];
#pragma unroll
    for (int r = 0; r < 4; r++) {
        int s = w + 4 * r;
        kr[r] = *(const short8v*)&ksrc[(jbeg + (s >> 3) * 32 + l31) * HH + (s & 7) * 16 + hi * 8];
        vr[r] = *(const short8v*)&vsrc[((s >> 2) * 32 + l31) * LL + jbeg + (s & 3) * 16 + hi * 8];
    }

    for (int c = 0; c < nchunk; c++) {
        __syncthreads();
#pragma unroll
        for (int r = 0; r < 4; r++) {
            int s = w + 4 * r;
            *(short8v*)&sK[(s * 64 + lane) * 8] = kr[r];
            *(short8v*)&sV[(s * 64 + lane) * 8] = vr[r];
        }
        __syncthreads();
        if (c + 1 < nchunk) {
            const int j1 = jbeg + (c + 1) * FBN;
#pragma unroll
            for (int r = 0; r < 4; r++) {
                int s = w + 4 * r;
                kr[r] = *(const short8v*)&ksrc[(j1 + (s >> 3) * 32 + l31) * HH + (s & 7) * 16 + hi * 8];
                vr[r] = *(const short8v*)&vsrc[((s >> 2) * 32 + l31) * LL + j1 + (s & 3) * 16 + hi * 8];
            }
        }
        // ---- S^T = K Q^T ----
        f32x16 s0 = (f32x16)(0.f), s1 = (f32x16)(0.f);
        __builtin_amdgcn_s_setprio(1);
#pragma unroll
        for (int ks = 0; ks < 8; ks++) {
            short8v kf0 = *(const short8v*)&sK[((ks) * 64 + lane) * 8];
            short8v kf1 = *(const short8v*)&sK[((8 + ks) * 64 + lane) * 8];
            s0 = __builtin_amdgcn_mfma_f32_32x32x16_bf16(kf0, qf[ks], s0, 0, 0, 0);
            s1 = __builtin_amdgcn_mfma_f32_32x32x16_bf16(kf1, qf[ks], s1, 0, 0, 0);
        }
        __builtin_amdgcn_s_setprio(0);
        // ---- softmax + in-register P->A-frag (per 32-kv tile, T12) ----
        short8v pfrag[4];
#pragma unroll
        for (int nt = 0; nt < 2; nt++) {
            const f32x16& sa = nt ? s1 : s0;
            unsigned pw[8];
#pragma unroll
            for (int m = 0; m < 8; m++) {
                float p0 = fexp2(sa[2 * m]);
                float p1 = fexp2(sa[2 * m + 1]);
                l_r += p0 + p1;
                union { float f; unsigned u; } u0, u1;
                u0.f = p0; u1.f = p1;
                pw[m] = pack_hi16(u1.u, u0.u);
            }
            plane32swap(pw[0], pw[2]);
            plane32swap(pw[1], pw[3]);
            plane32swap(pw[4], pw[6]);
            plane32swap(pw[5], pw[7]);
            union { unsigned u[4]; short8v v; } fa, fb;
            fa.u[0] = pw[0]; fa.u[1] = pw[1]; fa.u[2] = pw[2]; fa.u[3] = pw[3];
            fb.u[0] = pw[4]; fb.u[1] = pw[5]; fb.u[2] = pw[6]; fb.u[3] = pw[7];
            pfrag[nt * 2]     = fa.v;
            pfrag[nt * 2 + 1] = fb.v;
        }
        // ---- O += P V ----
        __builtin_amdgcn_s_setprio(1);
#pragma unroll
        for (int ks = 0; ks < 4; ks++)
#pragma unroll
            for (int dt = 0; dt < 4; dt++) {
                short8v vf = *(const short8v*)&sV[((dt * 4 + ks) * 64 + lane) * 8];
                o_acc[dt] = __builtin_amdgcn_mfma_f32_32x32x16_bf16(pfrag[ks], vf, o_acc[dt], 0, 0, 0);
            }
        __builtin_amdgcn_s_setprio(0);
    }
    // ---- finalize l ----
    float lsum = l_r + __shfl_xor(l_r, 32, 64);
    if (hi == 0)
        Pl[seg * LL + qrow] = lsum;
    // ---- write bf16 partials ----
#pragma unroll
    for (int dt = 0; dt < 4; dt++)
#pragma unroll
        for (int i = 0; i < 16; i++) {
            int qr = (i & 3) + 8 * (i >> 2) + 4 * hi;
            PO[(size_t)seg * LL * HH + (size_t)(m0 + w * 32 + qr) * HH + dt * 32 + l31] =
                f2bf(o_acc[dt][i]);
        }
}

// ---------------------------------------------------------------------------
// ff v2, 2 phases (was ~5): each 16-lane group owns ONE row end-to-end in
// registers -- Pl-sum, PO-merge (one short8v per seg), residual, LN all
// in-register (LN layout == merge layout) -> single LDS write of merged
// (sF, for the out-residual) + normed (sA) -> ONE barrier -> FF GEMM + out.
// ---------------------------------------------------------------------------
__global__ __launch_bounds__(256) void ff_kernel(const float* __restrict__ hin,
                                                 const short* __restrict__ PO,
                                                 const float* __restrict__ Pl,
                                                 const short* __restrict__ wffb,
                                                 const float* __restrict__ bff,
                                                 float* __restrict__ out) {
    __shared__ float sF[16][132];
    __shared__ short sA[16 * 128];
    int tid = threadIdx.x;
    int w = tid >> 6, lane = tid & 63;
    int l15 = lane & 15, quad = lane >> 4;
    int wg = blockIdx.x;
    int m0 = ((wg & 7) * 64 + (wg >> 3)) * 16;
    int row = w * 4 + quad;          // this group's row (0..15)
    int grow = m0 + row;

    // Pl sum (uniform per group; 8 independent broadcast loads)
    float s = 0.f;
#pragma unroll
    for (int seg = 0; seg < NSPLIT; seg++) s += Pl[seg * LL + grow];
    float li = 1.f / s;

    // merge PO segs + residual, fully in registers
    float acc[8] = {0.f, 0.f, 0.f, 0.f, 0.f, 0.f, 0.f, 0.f};
#pragma unroll
    for (int seg = 0; seg < NSPLIT; seg++) {
        short8v pv = *(const short8v*)&PO[(size_t)seg * LL * HH + (size_t)grow * HH + l15 * 8];
#pragma unroll
        for (int j = 0; j < 8; j++) acc[j] += bf2f(pv[j]);
    }
    float4 h0v = *(const float4*)&hin[grow * HH + l15 * 8];
    float4 h1v = *(const float4*)&hin[grow * HH + l15 * 8 + 4];
    float m[8];
    m[0] = h0v.x + acc[0] * li; m[1] = h0v.y + acc[1] * li;
    m[2] = h0v.z + acc[2] * li; m[3] = h0v.w + acc[3] * li;
    m[4] = h1v.x + acc[4] * li; m[5] = h1v.y + acc[5] * li;
    m[6] = h1v.z + acc[6] * li; m[7] = h1v.w + acc[7] * li;
    *(float4*)&sF[row][l15 * 8]     = make_float4(m[0], m[1], m[2], m[3]);
    *(float4*)&sF[row][l15 * 8 + 4] = make_float4(m[4], m[5], m[6], m[7]);
    // LN in registers (4-level intra-group reduce)
    {
        float ss  = (m[0] + m[1]) + (m[2] + m[3]) + (m[4] + m[5]) + (m[6] + m[7]);
        float ss2 = m[0]*m[0] + m[1]*m[1] + m[2]*m[2] + m[3]*m[3]
                  + m[4]*m[4] + m[5]*m[5] + m[6]*m[6] + m[7]*m[7];
#pragma unroll
        for (int off = 1; off <= 8; off <<= 1) {
            ss  += __shfl_xor(ss,  off, 64);
            ss2 += __shfl_xor(ss2, off, 64);
        }
        float mu = ss * (1.f / 128.f);
        float var = ss2 * (1.f / 128.f) - mu * mu;
        float rstd = rsqrtf(var + 1e-5f);
        short8v r;
#pragma unroll
        for (int j = 0; j < 8; j++) r[j] = f2bf((m[j] - mu) * rstd);
        *(short8v*)sAp(sA, row, l15 * 8) = r;
    }
    __syncthreads();
    // ---- FF GEMM + relu + residual -> out ----
    int c0 = w * 32;
    f32x4 acc0 = (f32x4)(0.f), acc1 = (f32x4)(0.f);
    const short* b0 = wffb + (c0 + l15) * HH;
    const short* b1 = b0 + 16 * HH;
#pragma unroll
    for (int ks = 0; ks < 4; ks++) {
        short8v af = *(const short8v*)sAp(sA, l15, ks * 32 + quad * 8);
        short8v bf0 = *(const short8v*)&b0[ks * 32 + quad * 8];
        short8v bf1 = *(const short8v*)&b1[ks * 32 + quad * 8];
        acc0 = __builtin_amdgcn_mfma_f32_16x16x32_bf16(af, bf0, acc0, 0, 0, 0);
        acc1 = __builtin_amdgcn_mfma_f32_16x16x32_bf16(af, bf1, acc1, 0, 0, 0);
    }
    float bb0 = bff[c0 + l15], bb1 = bff[c0 + 16 + l15];
#pragma unroll
    for (int r = 0; r < 4; r++) {
        int lr = quad * 4 + r;
        out[(m0 + lr) * HH + c0 + l15]      = fmaxf(acc0[r] + bb0, 0.f) + sF[lr][c0 + l15];
        out[(m0 + lr) * HH + c0 + 16 + l15] = fmaxf(acc1[r] + bb1, 0.f) + sF[lr][c0 + 16 + l15];
    }
}

// ---------------------------------------------------------------------------
extern "C" void kernel_launch(void* const* d_in, const int* in_sizes, int n_in,
                              void* d_out, int out_size, void* d_ws, size_t ws_size,
                              hipStream_t stream) {
    const float* x      = (const float*)d_in[0];
    const float* conv_w = (const float*)d_in[1];
    const float* conv_b = (const float*)d_in[2];
    const float* Wq = (const float*)d_in[3];
    const float* bq = (const float*)d_in[4];
    const float* Wk = (const float*)d_in[5];
    const float* bk = (const float*)d_in[6];
    const float* Wv = (const float*)d_in[7];
    const float* bv = (const float*)d_in[8];
    const float* Wff = (const float*)d_in[9];
    const float* bff = (const float*)d_in[10];
    float* out = (float*)d_out;

    char* ws = (char*)d_ws;
    const size_t MB = 1u << 20;
    float* hB   = (float*)(ws);                              // 4 MB (h4, lives to end)
    short* qb   = (short*)(ws + 4 * MB);                     // 2 MB
    short* kb   = (short*)(ws + 6 * MB);                     // 2 MB
    short* vt   = (short*)(ws + 8 * MB);                     // 2 MB
    float* Pl   = (float*)(ws + 10 * MB);                    // 256 KB (8 segs)
    short* wffb = (short*)(ws + 10 * MB + 524288);           // 32 KB
    short* PO   = (short*)(ws + 10 * MB + 524288 + 32768);   // 16 MB bf16 (nsplit=8)
    // pre-flash-only buffers, aliased inside the PO span (dead before flash):
    short* wkb   = (short*)(ws + 16 * MB);                   // 896 KB
    short* wqkvb = (short*)(ws + 17 * MB);                   // 96 KB
    float* b3    = (float*)(ws + 17 * MB + 131072);          // 1.5 KB

    repack_all<<<2050, 256, 0, stream>>>(conv_w, Wq, Wk, Wv, bq, bk, bv, Wff,
                                         wkb, wqkvb, b3, wffb);
    conv4_qkv_kernel<<<LL / 16, 256, 0, stream>>>(x, wkb, conv_b, wqkvb, b3,
                                                  hB, qb, kb, vt);
    flash_mfma_kernel<<<LL / 128 * NSPLIT, 256, 0, stream>>>(qb, kb, vt, PO, Pl);
    ff_kernel<<<LL / 16, 256, 0, stream>>>(hB, PO, Pl, wffb, bff, out);
}